// Round 3
// baseline (246.884 us; speedup 1.0000x reference)
//
#include <hip/hip_runtime.h>

#define B_ 4
#define D_ 4
#define P_ 12000
#define N_ 100
#define C_ 64
#define GH 496
#define GW 432
#define PN (P_*N_)        /* 1,200,000 */
#define HW (GH*GW)        /* 214,272   */
#define WPB 12            /* waves per fused block */
#define PPB (WPB*8)       /* 96 pillars per fused block */
#define GRID_F (B_*(P_/PPB))  /* 500 fused blocks */
#define OVFCAP 4096           /* collision-overflow capacity (expected ~1.5k) */
#define OUT_CHUNK 2304        /* 9*256 cells; HW == 2304*93 */
#define OUT_NCH (HW/OUT_CHUNK)/* 93 */

typedef float v2f __attribute__((ext_vector_type(2)));

// Packed f32 fma (v_pk_fma_f32 on CDNA); scalar fallback keeps identical numerics.
#if defined(__has_builtin)
#if __has_builtin(__builtin_elementwise_fma)
#define HAVE_EW_FMA 1
#endif
#endif
__device__ __forceinline__ v2f fma2(v2f a, v2f b, v2f c) {
#ifdef HAVE_EW_FMA
    return __builtin_elementwise_fma(a, b, c);
#else
    v2f r; r.x = fmaf(a.x, b.x, c.x); r.y = fmaf(a.y, b.y, c.y); return r;
#endif
}
__device__ __forceinline__ v2f max2(v2f a, v2f b) {
    v2f r; r.x = fmaxf(a.x, b.x); r.y = fmaxf(a.y, b.y); return r;
}

// ---- workspace layout (total 15,733,760 B, under the proven 15.77 MB envelope) ----
static constexpr size_t OFF_ST    = 0;                          // st[c] = {sc, shift} (512 B)
static constexpr size_t OFF_CTL   = 512;                        // +0 ovfcnt(i32) +4 done(i32) +64 momacc[14] f64
static constexpr size_t OFF_SLOT  = 1024;
static constexpr size_t SLOT_BYTES= (size_t)B_*HW*4;            // 3,428,352
static constexpr size_t OFF_OVF   = OFF_SLOT + SLOT_BYTES;      // 3,429,376
static constexpr size_t OFF_U     = OFF_OVF + (size_t)OVFCAP*4; // 3,445,760
static constexpr size_t U_BYTES   = (size_t)B_*P_*C_*4;         // 12,288,000

// VALU-only 8-lane-group max reduction step
template<int CTRL>
__device__ __forceinline__ float dppmax(float v) {
    int s = __builtin_amdgcn_update_dpp(0, __float_as_int(v), CTRL, 0xf, 0xf, true);
    return fmaxf(v, __int_as_float(s));
}

// Slot allocation: DETERMINISTIC winner = max pillar id per cell (atomicMax).
__global__ __launch_bounds__(256) void k_alloc(const int* __restrict__ idx,
                                               int* __restrict__ slot,
                                               int* __restrict__ ovf,
                                               int* __restrict__ ovfcnt) {
    const int BPB = (P_ + 255)/256;           // 47 blocks per batch
    int b = blockIdx.x / BPB;
    int p = (blockIdx.x % BPB)*256 + threadIdx.x;
    if (p >= P_) return;
    size_t bp = (size_t)b*P_ + p;
    int h = idx[bp*2], w = idx[bp*2 + 1];
    int cell = h*GW + w;
    int old = atomicMax(&slot[(size_t)b*HW + cell], p);
    if (old != -1) {                          // collision: smaller of {old,p} loses
        int loser = (old < p) ? old : p;
        int at = atomicAdd(ovfcnt, 1);
        if (at < OVFCAP) ovf[at] = b*P_ + loser;
    }
}

// Fused single x pass: BN moment partials (f64 atomic accum + last-block stats)
// and raw per-pillar conv maxes u[b][p][c] = max_n (W[c,:]·x[:,p,n]).
// Affine+relu deferred to k_out/k_fixup (sc > 0 so max commutes with affine).
__global__ __launch_bounds__(768) void k_fused(const float* __restrict__ x,
                                               const float* __restrict__ Wm,
                                               const float* __restrict__ gamma,
                                               const float* __restrict__ beta,
                                               int* __restrict__ done,
                                               double* __restrict__ momacc,
                                               float* __restrict__ st,
                                               float* __restrict__ uraw) {
    __shared__ float tr[WPB][8*65 + 8];       // per-wave transpose, pad vs banks
    __shared__ float red[WPB][14];
    __shared__ int   slastf;
    const int BPB = P_/PPB;                   // 125 blocks per batch
    int b    = blockIdx.x / BPB;
    int pblk = (blockIdx.x % BPB)*PPB;
    int lane = threadIdx.x & 63;
    int wv   = threadIdx.x >> 6;
    int pl   = lane >> 3;
    int oct  = lane & 7;
    int p    = pblk + wv*8 + pl;
    const float* xb = x + (size_t)b*D_*PN + (size_t)p*N_;

    float4 xq[3][4];                          // [j][d]
    #pragma unroll
    for (int j = 0; j < 3; ++j) {
        int n = 4*oct + 32*j;
        #pragma unroll
        for (int d = 0; d < 4; ++d)
            xq[j][d] = *reinterpret_cast<const float4*>(xb + n + (size_t)d*PN);
    }
    float x13[4];                             // tail slot
    #pragma unroll
    for (int d = 0; d < 4; ++d)
        x13[d] = (oct < 4) ? xb[96 + oct + (size_t)d*PN] : xq[0][d].x;

    // ---- moments (packed): s01={s0,s1} s23={s2,s3}, a0={m00,m11} a1={m01,m12}
    // a2={m02,m13} a3={m03,m23} a4={m22,m33}. Same fma per component as before.
    {
        v2f s01 = {0.f,0.f}, s23 = {0.f,0.f};
        v2f a0 = {0.f,0.f}, a1 = {0.f,0.f}, a2 = {0.f,0.f}, a3 = {0.f,0.f}, a4 = {0.f,0.f};
        #pragma unroll
        for (int j = 0; j < 3; ++j) {
            #pragma unroll
            for (int e = 0; e < 4; ++e) {
                float x0 = ((const float*)&xq[j][0])[e];
                float x1 = ((const float*)&xq[j][1])[e];
                float x2 = ((const float*)&xq[j][2])[e];
                float x3 = ((const float*)&xq[j][3])[e];
                v2f q01 = {x0,x1}, q12 = {x1,x2}, q23 = {x2,x3}, q02 = {x0,x2}, q33 = {x3,x3};
                s01 += q01; s23 += q23;
                a0 = fma2(q01, q01, a0);
                a1 = fma2(q01, q12, a1);
                a2 = fma2(q01, q23, a2);
                a3 = fma2(q02, q33, a3);
                a4 = fma2(q23, q23, a4);
            }
        }
        if (oct < 4) {                        // genuine tail n = 96..99
            float x0 = x13[0], x1 = x13[1], x2 = x13[2], x3 = x13[3];
            v2f q01 = {x0,x1}, q12 = {x1,x2}, q23 = {x2,x3}, q02 = {x0,x2}, q33 = {x3,x3};
            s01 += q01; s23 += q23;
            a0 = fma2(q01, q01, a0);
            a1 = fma2(q01, q12, a1);
            a2 = fma2(q01, q23, a2);
            a3 = fma2(q02, q33, a3);
            a4 = fma2(q23, q23, a4);
        }
        float v[14] = {s01.x, s01.y, s23.x, s23.y,
                       a0.x, a1.x, a2.x, a3.x,      /* m00 m01 m02 m03 */
                       a0.y, a1.y, a2.y,            /* m11 m12 m13 */
                       a4.x, a3.y, a4.y};           /* m22 m23 m33 */
        #pragma unroll
        for (int j = 0; j < 14; ++j) {
            float t = v[j];
            #pragma unroll
            for (int off = 32; off; off >>= 1) t += __shfl_down(t, off);
            if (lane == 0) red[wv][j] = t;
        }
        __syncthreads();
        if (threadIdx.x < 14) {
            int j = threadIdx.x;
            float t = 0.f;
            #pragma unroll
            for (int w2 = 0; w2 < WPB; ++w2) t += red[w2][j];
            atomicAdd(&momacc[j], (double)t);
        }
    }
    // ---- last-block-done: compute st once, hidden under other blocks' conv ----
    __threadfence();                          // momacc adds globally visible (wave0 ops)
    if (threadIdx.x == 0) slastf = (atomicAdd(done, 1) == GRID_F - 1);
    __syncthreads();
    if (slastf) {                             // block-uniform branch
        __shared__ double smom[14];
        if (threadIdx.x < 14)
            smom[threadIdx.x] = atomicAdd(&momacc[threadIdx.x], 0.0);  // coherent read
        __syncthreads();
        if (threadIdx.x < C_) {
            int c = threadIdx.x;
            double S[4];
            #pragma unroll
            for (int d = 0; d < 4; ++d) S[d] = smom[d];
            double M[4][4];
            int k = 4;
            for (int i = 0; i < 4; ++i)
                for (int j = i; j < 4; ++j) { M[i][j] = smom[k]; M[j][i] = smom[k]; ++k; }
            double w[4];
            #pragma unroll
            for (int d = 0; d < 4; ++d) w[d] = (double)Wm[c*4+d];
            const double NT = (double)B_ * (double)PN;
            double mean = 0.0;
            #pragma unroll
            for (int d = 0; d < 4; ++d) mean += w[d]*S[d];
            mean /= NT;
            double ey2 = 0.0;
            for (int i = 0; i < 4; ++i)
                for (int j = 0; j < 4; ++j) ey2 += w[i]*w[j]*M[i][j];
            ey2 /= NT;
            double var = ey2 - mean*mean;
            double inv = 1.0 / sqrt(var + 1e-5);
            double sc  = (double)gamma[c] * inv;
            st[c*2]     = (float)sc;
            st[c*2 + 1] = (float)((double)beta[c] - mean*sc);
        }
    }

    // ---- conv-max, channel-pair packed (identical fma nesting per component) ----
    for (int c = 0; c < C_; c += 2) {
        const float4 wA = *reinterpret_cast<const float4*>(Wm + c*4);
        const float4 wB = *reinterpret_cast<const float4*>(Wm + (c+1)*4);
        v2f wp0 = {wA.x, wB.x}, wp1 = {wA.y, wB.y};
        v2f wp2 = {wA.z, wB.z}, wp3 = {wA.w, wB.w};
        v2f m = {-3.4e38f, -3.4e38f};
        #pragma unroll
        for (int j = 0; j < 3; ++j) {
            #pragma unroll
            for (int e = 0; e < 4; ++e) {
                float v0 = ((const float*)&xq[j][0])[e];
                float v1 = ((const float*)&xq[j][1])[e];
                float v2 = ((const float*)&xq[j][2])[e];
                float v3 = ((const float*)&xq[j][3])[e];
                v2f dot = wp3 * v3;           // scalar splat
                dot = fma2(wp2, v2f{v2, v2}, dot);
                dot = fma2(wp1, v2f{v1, v1}, dot);
                dot = fma2(wp0, v2f{v0, v0}, dot);
                m = max2(m, dot);
            }
        }
        {
            v2f dot = wp3 * x13[3];
            dot = fma2(wp2, v2f{x13[2], x13[2]}, dot);
            dot = fma2(wp1, v2f{x13[1], x13[1]}, dot);
            dot = fma2(wp0, v2f{x13[0], x13[0]}, dot);
            m = max2(m, dot);
        }
        float mA = m.x, mB = m.y;
        mA = dppmax<0xB1>(mA); mA = dppmax<0x4E>(mA); mA = dppmax<0x141>(mA);
        mB = dppmax<0xB1>(mB); mB = dppmax<0x4E>(mB); mB = dppmax<0x141>(mB);
        if (oct == (c >> 3)) {                // c even: both c, c+1 same octant
            tr[wv][pl*65 + c]     = mA;
            tr[wv][pl*65 + c + 1] = mB;
        }
    }
    __builtin_amdgcn_s_waitcnt(0);            // drain LDS writes (wave-local use)
    for (int pi = 0; pi < 8; ++pi)
        uraw[((size_t)b*P_ + pblk + wv*8 + pi)*C_ + lane] = tr[wv][pi*65 + lane];
}

// Output streamer v2: block = (b, channel-pair, 2304-cell chunk).
// Writes two 9 KB CONTIGUOUS runs per block (long DRAM bursts), no LDS.
// slot re-read x32 through LLC (3.4 MB hot); uraw gather = 8 B float2, LLC-resident.
__global__ __launch_bounds__(256) void k_out(const int* __restrict__ slot,
                                             const float* __restrict__ uraw,
                                             const float* __restrict__ st,
                                             float* __restrict__ out) {
    int bid   = blockIdx.x;
    int chunk = bid % OUT_NCH;
    int cp    = (bid / OUT_NCH) % (C_/2);
    int b     = bid / (OUT_NCH*(C_/2));
    int c     = cp*2;
    int cell0 = chunk*OUT_CHUNK;
    const float4 s4 = *reinterpret_cast<const float4*>(st + c*2); // {scA,shA,scB,shB}
    const int*    sl  = slot + (size_t)b*HW + cell0;
    const float2* vb2 = reinterpret_cast<const float2*>(uraw + (size_t)b*P_*C_);
    float* oA = out + ((size_t)b*C_ + c    )*HW + cell0;
    float* oB = out + ((size_t)b*C_ + c + 1)*HW + cell0;
    int t = threadIdx.x;
    #pragma unroll
    for (int i = 0; i < OUT_CHUNK/256; ++i) {
        int cell = i*256 + t;
        int s = sl[cell];
        float yA = 0.f, yB = 0.f;
        if (s >= 0) {
            float2 u = vb2[(size_t)s*(C_/2) + cp];
            yA = fmaxf(fmaf(s4.x, u.x, s4.y), 0.f);
            yB = fmaxf(fmaf(s4.z, u.y, s4.w), 0.f);
        }
        oA[cell] = yA;
        oB[cell] = yB;
    }
}

// Add collision losers' affine+relu'd rows directly into out (after k_out).
__global__ __launch_bounds__(256) void k_fixup(const int* __restrict__ ovf,
                                               const int* __restrict__ ovfcnt,
                                               const int* __restrict__ idx,
                                               const float* __restrict__ uraw,
                                               const float* __restrict__ st,
                                               float* __restrict__ out) {
    int n = *ovfcnt;
    if (n > OVFCAP) n = OVFCAP;
    int lane = threadIdx.x & 63;
    int wid  = (blockIdx.x*256 + threadIdx.x) >> 6;
    int nw   = gridDim.x*4;
    float2 ss = *reinterpret_cast<const float2*>(st + lane*2);
    for (int e = wid; e < n; e += nw) {
        int bp = ovf[e];
        int b  = bp / P_;
        int h = idx[(size_t)bp*2], w = idx[(size_t)bp*2 + 1];
        int cell = h*GW + w;
        float u = uraw[(size_t)bp*C_ + lane];
        float y = fmaxf(fmaf(ss.x, u, ss.y), 0.0f);
        if (y > 0.0f)
            atomicAdd(&out[((size_t)b*C_ + lane)*HW + cell], y);
    }
}

extern "C" void kernel_launch(void* const* d_in, const int* in_sizes, int n_in,
                              void* d_out, int out_size, void* d_ws, size_t ws_size,
                              hipStream_t stream) {
    const float* x     = (const float*)d_in[0];
    const int*   idx   = (const int*)  d_in[1];
    const float* Wm    = (const float*)d_in[2];
    const float* gamma = (const float*)d_in[3];
    const float* beta  = (const float*)d_in[4];
    float* out = (float*)d_out;

    char* ws = (char*)d_ws;
    float*  st     = (float*) (ws + OFF_ST);
    int*    ovfcnt = (int*)   (ws + OFF_CTL);
    int*    done   = (int*)   (ws + OFF_CTL + 4);
    double* momacc = (double*)(ws + OFF_CTL + 64);
    int*    slot   = (int*)   (ws + OFF_SLOT);
    int*    ovf    = (int*)   (ws + OFF_OVF);
    float*  uraw   = (float*) (ws + OFF_U);

    hipMemsetAsync(ws + OFF_SLOT, 0xFF, SLOT_BYTES, stream);   // slot <- -1
    hipMemsetAsync(ws + OFF_CTL, 0, 256, stream);              // ovfcnt, done, momacc <- 0
    k_alloc<<<B_*((P_ + 255)/256), 256, 0, stream>>>(idx, slot, ovf, ovfcnt);
    k_fused<<<GRID_F, WPB*64, 0, stream>>>(x, Wm, gamma, beta, done, momacc, st, uraw);
    k_out  <<<B_*(C_/2)*OUT_NCH, 256, 0, stream>>>(slot, uraw, st, out);
    k_fixup<<<32, 256, 0, stream>>>(ovf, ovfcnt, idx, uraw, st, out);
}

// Round 4
// 149.965 us; speedup vs baseline: 1.6463x; 1.6463x over previous
//
#include <hip/hip_runtime.h>

#define B_ 4
#define D_ 4
#define P_ 12000
#define N_ 100
#define C_ 64
#define GH 496
#define GW 432
#define PN (P_*N_)        /* 1,200,000 */
#define HW (GH*GW)        /* 214,272   */
#define WPB 12            /* waves per fused block */
#define PPB (WPB*8)       /* 96 pillars per fused block */
#define GRID_F (B_*(P_/PPB))  /* 500 fused blocks; partials stride */
#define OVFCAP 4096           /* collision-overflow capacity (expected ~1.5k) */
#define OCH 768               /* k_out cells per block; HW == 768*279 */
#define ONCH (HW/OCH)         /* 279 */

typedef float v2f __attribute__((ext_vector_type(2)));

// Packed f32 fma (v_pk_fma_f32 on CDNA); scalar fallback keeps identical numerics.
#if defined(__has_builtin)
#if __has_builtin(__builtin_elementwise_fma)
#define HAVE_EW_FMA 1
#endif
#endif
__device__ __forceinline__ v2f fma2(v2f a, v2f b, v2f c) {
#ifdef HAVE_EW_FMA
    return __builtin_elementwise_fma(a, b, c);
#else
    v2f r; r.x = fmaf(a.x, b.x, c.x); r.y = fmaf(a.y, b.y, c.y); return r;
#endif
}
__device__ __forceinline__ v2f max2(v2f a, v2f b) {
    v2f r; r.x = fmaxf(a.x, b.x); r.y = fmaxf(a.y, b.y); return r;
}

// ---- workspace layout (total 15,761,408 B, under the proven 15.77 MB envelope) ----
static constexpr size_t OFF_ST    = 0;                          // st[c] = {sc, shift} (512 B)
static constexpr size_t OFF_PART  = 512;                        // partials [14][GRID_F] f32
static constexpr size_t PART_BYTES= 14*(size_t)GRID_F*4;        // 28,000
static constexpr size_t OFF_CTL   = (OFF_PART + PART_BYTES + 63) & ~(size_t)63;  // ovfcnt
static constexpr size_t OFF_SLOT  = 28672;
static constexpr size_t SLOT_BYTES= (size_t)B_*HW*4;            // 3,428,352
static constexpr size_t OFF_OVF   = OFF_SLOT + SLOT_BYTES;      // 3,457,024
static constexpr size_t OFF_U     = OFF_OVF + (size_t)OVFCAP*4; // 3,473,408 (256-aligned)
static constexpr size_t U_BYTES   = (size_t)B_*P_*C_*4;         // 12,288,000

// VALU-only 8-lane-group max reduction step
template<int CTRL>
__device__ __forceinline__ float dppmax(float v) {
    int s = __builtin_amdgcn_update_dpp(0, __float_as_int(v), CTRL, 0xf, 0xf, true);
    return fmaxf(v, __int_as_float(s));
}

// Slot allocation: DETERMINISTIC winner = max pillar id per cell (atomicMax).
__global__ __launch_bounds__(256) void k_alloc(const int* __restrict__ idx,
                                               int* __restrict__ slot,
                                               int* __restrict__ ovf,
                                               int* __restrict__ ovfcnt) {
    const int BPB = (P_ + 255)/256;           // 47 blocks per batch
    int b = blockIdx.x / BPB;
    int p = (blockIdx.x % BPB)*256 + threadIdx.x;
    if (p >= P_) return;
    size_t bp = (size_t)b*P_ + p;
    int h = idx[bp*2], w = idx[bp*2 + 1];
    int cell = h*GW + w;
    int old = atomicMax(&slot[(size_t)b*HW + cell], p);
    if (old != -1) {                          // collision: smaller of {old,p} loses
        int loser = (old < p) ? old : p;
        int at = atomicAdd(ovfcnt, 1);
        if (at < OVFCAP) ovf[at] = b*P_ + loser;
    }
}

// Fused single x pass: BN moment partials (per-block f32 slot, NO atomics/fences)
// and raw per-pillar conv maxes u[b][p][c] = max_n (W[c,:]·x[:,p,n]).
// Affine+relu deferred to k_out/k_fixup (sc > 0 so max commutes with affine).
__global__ __launch_bounds__(768) void k_fused(const float* __restrict__ x,
                                               const float* __restrict__ Wm,
                                               float* __restrict__ partials,
                                               float* __restrict__ uraw) {
    __shared__ float tr[WPB][8*65 + 8];       // per-wave transpose, pad vs banks
    __shared__ float red[WPB][14];
    const int BPB = P_/PPB;                   // 125 blocks per batch
    int b    = blockIdx.x / BPB;
    int pblk = (blockIdx.x % BPB)*PPB;
    int lane = threadIdx.x & 63;
    int wv   = threadIdx.x >> 6;
    int pl   = lane >> 3;
    int oct  = lane & 7;
    int p    = pblk + wv*8 + pl;
    const float* xb = x + (size_t)b*D_*PN + (size_t)p*N_;

    float4 xq[3][4];                          // [j][d]
    #pragma unroll
    for (int j = 0; j < 3; ++j) {
        int n = 4*oct + 32*j;
        #pragma unroll
        for (int d = 0; d < 4; ++d)
            xq[j][d] = *reinterpret_cast<const float4*>(xb + n + (size_t)d*PN);
    }
    float x13[4];                             // tail slot
    #pragma unroll
    for (int d = 0; d < 4; ++d)
        x13[d] = (oct < 4) ? xb[96 + oct + (size_t)d*PN] : xq[0][d].x;

    // ---- moments (packed): s01={s0,s1} s23={s2,s3}, a0={m00,m11} a1={m01,m12}
    // a2={m02,m13} a3={m03,m23} a4={m22,m33}.
    {
        v2f s01 = {0.f,0.f}, s23 = {0.f,0.f};
        v2f a0 = {0.f,0.f}, a1 = {0.f,0.f}, a2 = {0.f,0.f}, a3 = {0.f,0.f}, a4 = {0.f,0.f};
        #pragma unroll
        for (int j = 0; j < 3; ++j) {
            #pragma unroll
            for (int e = 0; e < 4; ++e) {
                float x0 = ((const float*)&xq[j][0])[e];
                float x1 = ((const float*)&xq[j][1])[e];
                float x2 = ((const float*)&xq[j][2])[e];
                float x3 = ((const float*)&xq[j][3])[e];
                v2f q01 = {x0,x1}, q12 = {x1,x2}, q23 = {x2,x3}, q02 = {x0,x2}, q33 = {x3,x3};
                s01 += q01; s23 += q23;
                a0 = fma2(q01, q01, a0);
                a1 = fma2(q01, q12, a1);
                a2 = fma2(q01, q23, a2);
                a3 = fma2(q02, q33, a3);
                a4 = fma2(q23, q23, a4);
            }
        }
        if (oct < 4) {                        // genuine tail n = 96..99
            float x0 = x13[0], x1 = x13[1], x2 = x13[2], x3 = x13[3];
            v2f q01 = {x0,x1}, q12 = {x1,x2}, q23 = {x2,x3}, q02 = {x0,x2}, q33 = {x3,x3};
            s01 += q01; s23 += q23;
            a0 = fma2(q01, q01, a0);
            a1 = fma2(q01, q12, a1);
            a2 = fma2(q01, q23, a2);
            a3 = fma2(q02, q33, a3);
            a4 = fma2(q23, q23, a4);
        }
        float v[14] = {s01.x, s01.y, s23.x, s23.y,
                       a0.x, a1.x, a2.x, a3.x,      /* m00 m01 m02 m03 */
                       a0.y, a1.y, a2.y,            /* m11 m12 m13 */
                       a4.x, a3.y, a4.y};           /* m22 m23 m33 */
        #pragma unroll
        for (int j = 0; j < 14; ++j) {
            float t = v[j];
            #pragma unroll
            for (int off = 32; off; off >>= 1) t += __shfl_down(t, off);
            if (lane == 0) red[wv][j] = t;
        }
        __syncthreads();
        if (threadIdx.x < 14) {
            int j = threadIdx.x;
            float t = 0.f;
            #pragma unroll
            for (int w2 = 0; w2 < WPB; ++w2) t += red[w2][j];
            partials[(size_t)j*GRID_F + blockIdx.x] = t;    // per-block slot, no atomics
        }
    }

    // ---- conv-max, channel-pair packed ----
    for (int c = 0; c < C_; c += 2) {
        const float4 wA = *reinterpret_cast<const float4*>(Wm + c*4);
        const float4 wB = *reinterpret_cast<const float4*>(Wm + (c+1)*4);
        v2f wp0 = {wA.x, wB.x}, wp1 = {wA.y, wB.y};
        v2f wp2 = {wA.z, wB.z}, wp3 = {wA.w, wB.w};
        v2f m = {-3.4e38f, -3.4e38f};
        #pragma unroll
        for (int j = 0; j < 3; ++j) {
            #pragma unroll
            for (int e = 0; e < 4; ++e) {
                float v0 = ((const float*)&xq[j][0])[e];
                float v1 = ((const float*)&xq[j][1])[e];
                float v2 = ((const float*)&xq[j][2])[e];
                float v3 = ((const float*)&xq[j][3])[e];
                v2f dot = wp3 * v3;
                dot = fma2(wp2, v2f{v2, v2}, dot);
                dot = fma2(wp1, v2f{v1, v1}, dot);
                dot = fma2(wp0, v2f{v0, v0}, dot);
                m = max2(m, dot);
            }
        }
        {
            v2f dot = wp3 * x13[3];
            dot = fma2(wp2, v2f{x13[2], x13[2]}, dot);
            dot = fma2(wp1, v2f{x13[1], x13[1]}, dot);
            dot = fma2(wp0, v2f{x13[0], x13[0]}, dot);
            m = max2(m, dot);
        }
        float mA = m.x, mB = m.y;
        mA = dppmax<0xB1>(mA); mA = dppmax<0x4E>(mA); mA = dppmax<0x141>(mA);
        mB = dppmax<0xB1>(mB); mB = dppmax<0x4E>(mB); mB = dppmax<0x141>(mB);
        if (oct == (c >> 3)) {                // c even: both c, c+1 same octant
            tr[wv][pl*65 + c]     = mA;
            tr[wv][pl*65 + c + 1] = mB;
        }
    }
    __builtin_amdgcn_s_waitcnt(0);            // drain LDS writes (wave-local use)
    for (int pi = 0; pi < 8; ++pi)
        uraw[((size_t)b*P_ + pblk + wv*8 + pi)*C_ + lane] = tr[wv][pi*65 + lane];
}

// Reduce moment partials in double, write per-channel {sc, shift}. Deterministic.
__global__ __launch_bounds__(256) void k_stats(const float* __restrict__ partials,
                                               const float* __restrict__ Wm,
                                               const float* __restrict__ gamma,
                                               const float* __restrict__ beta,
                                               float* __restrict__ st) {
    __shared__ double mom_s[14];
    __shared__ double redd[4];
    int lane = threadIdx.x & 63, wv = threadIdx.x >> 6;
    for (int j = 0; j < 14; ++j) {
        double s = 0.0;
        for (int i = threadIdx.x; i < GRID_F; i += 256)
            s += (double)partials[(size_t)j*GRID_F + i];
        #pragma unroll
        for (int off = 32; off; off >>= 1) s += __shfl_down(s, off);
        if (lane == 0) redd[wv] = s;
        __syncthreads();
        if (threadIdx.x == 0) mom_s[j] = redd[0]+redd[1]+redd[2]+redd[3];
        __syncthreads();
    }
    if (threadIdx.x < C_) {
        int c = threadIdx.x;
        double S[4];
        #pragma unroll
        for (int d = 0; d < 4; ++d) S[d] = mom_s[d];
        double M[4][4];
        int k = 4;
        for (int i = 0; i < 4; ++i)
            for (int j = i; j < 4; ++j) { M[i][j] = mom_s[k]; M[j][i] = mom_s[k]; ++k; }
        double w[4];
        #pragma unroll
        for (int d = 0; d < 4; ++d) w[d] = (double)Wm[c*4+d];
        const double NT = (double)B_ * (double)PN;
        double mean = 0.0;
        #pragma unroll
        for (int d = 0; d < 4; ++d) mean += w[d]*S[d];
        mean /= NT;
        double ey2 = 0.0;
        for (int i = 0; i < 4; ++i)
            for (int j = 0; j < 4; ++j) ey2 += w[i]*w[j]*M[i][j];
        ey2 /= NT;
        double var = ey2 - mean*mean;
        double inv = 1.0 / sqrt(var + 1e-5);
        double sc  = (double)gamma[c] * inv;
        st[c*2]     = (float)sc;
        st[c*2 + 1] = (float)((double)beta[c] - mean*sc);
    }
}

// Output streamer v3: block = (b, 768-cell chunk). slot chunk read ONCE into LDS.
// 8 channel-groups: winner rows (sparse, ~6% of cells) gathered as 2x float4;
// a block's ~43 winner rows fit L1, so all 8 groups reuse them. Writes are
// wave-coalesced 1 KB runs, 3 KB per channel per block. LDS tile c-major
// [8][OCH]: stride-1 conflict-free in both phases. LDS 27.7 KB -> 5 blocks/CU.
__global__ __launch_bounds__(256) void k_out(const int* __restrict__ slot,
                                             const float* __restrict__ uraw,
                                             const float* __restrict__ st,
                                             float* __restrict__ out) {
    __shared__ float tile[8][OCH];
    __shared__ int   sslot[OCH];
    int b     = blockIdx.x / ONCH;
    int chunk = blockIdx.x % ONCH;
    int cell0 = chunk*OCH;
    int t = threadIdx.x;
    #pragma unroll
    for (int k = 0; k < OCH/256; ++k)
        sslot[k*256 + t] = slot[(size_t)b*HW + cell0 + k*256 + t];
    __syncthreads();
    const float* vb = uraw + (size_t)b*P_*C_;
    for (int g = 0; g < 8; ++g) {
        #pragma unroll
        for (int k = 0; k < OCH/256; ++k) {
            int cell = k*256 + t;
            int s = sslot[cell];
            float4 u0 = {0.f,0.f,0.f,0.f}, u1 = {0.f,0.f,0.f,0.f};
            if (s >= 0) {
                const float* up = vb + (size_t)s*C_ + g*8;
                u0 = *reinterpret_cast<const float4*>(up);
                u1 = *reinterpret_cast<const float4*>(up + 4);
            }
            tile[0][cell] = u0.x; tile[1][cell] = u0.y;
            tile[2][cell] = u0.z; tile[3][cell] = u0.w;
            tile[4][cell] = u1.x; tile[5][cell] = u1.y;
            tile[6][cell] = u1.z; tile[7][cell] = u1.w;
        }
        __syncthreads();
        #pragma unroll
        for (int cp = 0; cp < 8; ++cp) {
            int c = g*8 + cp;
            float2 ss = *reinterpret_cast<const float2*>(st + c*2);
            float* ob = out + ((size_t)b*C_ + c)*HW + cell0;
            #pragma unroll
            for (int k = 0; k < OCH/256; ++k) {
                int cell = k*256 + t;
                float y = 0.f;
                if (sslot[cell] >= 0)
                    y = fmaxf(fmaf(ss.x, tile[cp][cell], ss.y), 0.f);
                ob[cell] = y;
            }
        }
        __syncthreads();
    }
}

// Add collision losers' affine+relu'd rows directly into out (after k_out).
__global__ __launch_bounds__(256) void k_fixup(const int* __restrict__ ovf,
                                               const int* __restrict__ ovfcnt,
                                               const int* __restrict__ idx,
                                               const float* __restrict__ uraw,
                                               const float* __restrict__ st,
                                               float* __restrict__ out) {
    int n = *ovfcnt;
    if (n > OVFCAP) n = OVFCAP;
    int lane = threadIdx.x & 63;
    int wid  = (blockIdx.x*256 + threadIdx.x) >> 6;
    int nw   = gridDim.x*4;
    float2 ss = *reinterpret_cast<const float2*>(st + lane*2);
    for (int e = wid; e < n; e += nw) {
        int bp = ovf[e];
        int b  = bp / P_;
        int h = idx[(size_t)bp*2], w = idx[(size_t)bp*2 + 1];
        int cell = h*GW + w;
        float u = uraw[(size_t)bp*C_ + lane];
        float y = fmaxf(fmaf(ss.x, u, ss.y), 0.0f);
        if (y > 0.0f)
            atomicAdd(&out[((size_t)b*C_ + lane)*HW + cell], y);
    }
}

extern "C" void kernel_launch(void* const* d_in, const int* in_sizes, int n_in,
                              void* d_out, int out_size, void* d_ws, size_t ws_size,
                              hipStream_t stream) {
    const float* x     = (const float*)d_in[0];
    const int*   idx   = (const int*)  d_in[1];
    const float* Wm    = (const float*)d_in[2];
    const float* gamma = (const float*)d_in[3];
    const float* beta  = (const float*)d_in[4];
    float* out = (float*)d_out;

    char* ws = (char*)d_ws;
    float* st       = (float*)(ws + OFF_ST);
    float* partials = (float*)(ws + OFF_PART);
    int*   ovfcnt   = (int*)  (ws + OFF_CTL);
    int*   slot     = (int*)  (ws + OFF_SLOT);
    int*   ovf      = (int*)  (ws + OFF_OVF);
    float* uraw     = (float*)(ws + OFF_U);

    hipMemsetAsync(ws + OFF_SLOT, 0xFF, SLOT_BYTES, stream);   // slot <- -1
    hipMemsetAsync(ws + OFF_CTL, 0, 64, stream);               // ovfcnt <- 0
    k_alloc<<<B_*((P_ + 255)/256), 256, 0, stream>>>(idx, slot, ovf, ovfcnt);
    k_fused<<<GRID_F, WPB*64, 0, stream>>>(x, Wm, partials, uraw);
    k_stats<<<1, 256, 0, stream>>>(partials, Wm, gamma, beta, st);
    k_out  <<<B_*ONCH, 256, 0, stream>>>(slot, uraw, st, out);
    k_fixup<<<32, 256, 0, stream>>>(ovf, ovfcnt, idx, uraw, st, out);
}